// Round 3
// baseline (8883.839 us; speedup 1.0000x reference)
//
#include <hip/hip_runtime.h>

#define BATCH 8
#define NPTS  2048
#define TPB   1024
#define WGB   64            // workgroups per batch
#define NWG   (BATCH*WGB)   // 512 = 2 per CU (64KB LDS, 16 waves -> exactly fits)
#define ITERS 50
#define R     4
#define HALF  1024          // columns per wave of a pair

#define KLOG2E    1442.6950408889634f    // log2(e)/eps
#define TWO_K     2885.3900817779268f    // 2*log2(e)/eps
#define INV_K     6.931471805599453e-4f  // eps*ln2 = 1/KLOG2E
#define INV_2K_SQ 1.2011325347955035e-7f // (1/(2K))^2
#define EPS_LN2   6.931471805599453e-4f  // eps*ln2
#define LN2       0.6931471805599453f
#define EPSV      1e-3f
#define NEGU      -1e30f
#define BIGD      1e10f

__device__ __forceinline__ float exp2fast(float x) { return __builtin_amdgcn_exp2f(x); }
__device__ __forceinline__ float log2fast(float x) { return __builtin_amdgcn_logf(x); }
__device__ __forceinline__ float clipf(float v)    { return fminf(fmaxf(v, -1.0f), 1.0f); }

__device__ __forceinline__ float wsum(float v) {
#pragma unroll
    for (int d = 1; d < 64; d <<= 1) v += __shfl_xor(v, d);
    return v;
}
__device__ __forceinline__ float wmax(float v) {
#pragma unroll
    for (int d = 1; d < 64; d <<= 1) v = fmaxf(v, __shfl_xor(v, d));
    return v;
}
__device__ __forceinline__ float wmin(float v) {
#pragma unroll
    for (int d = 1; d < 64; d <<= 1) v = fminf(v, __shfl_xor(v, d));
    return v;
}

// Sense-reversing per-batch barrier over WGB workgroups. Requires all WGs
// resident (guaranteed: grid == exact device capacity at this occupancy).
__device__ __forceinline__ void batch_barrier(int* cnt, int* gen, int tid)
{
    __syncthreads();                       // drains each wave's vmem (HIP emits vmcnt(0) before s_barrier)
    if (tid == 0) {
        __threadfence();                   // agent scope: publish WG's global writes across XCDs
        int g = __hip_atomic_load(gen, __ATOMIC_RELAXED, __HIP_MEMORY_SCOPE_AGENT);
        int a = __hip_atomic_fetch_add(cnt, 1, __ATOMIC_ACQ_REL, __HIP_MEMORY_SCOPE_AGENT);
        if (a == WGB - 1) {
            __hip_atomic_store(cnt, 0, __ATOMIC_RELAXED, __HIP_MEMORY_SCOPE_AGENT);
            __hip_atomic_store(gen, g + 1, __ATOMIC_RELEASE, __HIP_MEMORY_SCOPE_AGENT);
        } else {
            while (__hip_atomic_load(gen, __ATOMIC_ACQUIRE, __HIP_MEMORY_SCOPE_AGENT) == g)
                __builtin_amdgcn_s_sleep(2);
        }
    }
    __syncthreads();
}

// One half-iteration over THIS wave's column half [c0, c0+HALF) for R rows.
// Persistent per-half log2 reference L[]; exact two-pass redo on drift/seed.
// Pair (wv, wv^8) merges half-LSEs through scratch[].w (row-side LDS buffer,
// slots 0..63, whose .w is rewritten by the next phase anyway).
__device__ __forceinline__ void half_fused(const float4* __restrict__ colbuf,
                                           float4* __restrict__ scratch,
                                           const float* x0, const float* x1,
                                           const float* x2, const float* ar,
                                           float* __restrict__ outv, float* L,
                                           int nrows, int ncols, float eln,
                                           int r0, int lane, int wv, int h, int c0)
{
    const int ce  = min(ncols, c0 + HALF);
    const int nst = (ce > c0) ? ((ce - c0 + 63) >> 6) : 0;
    const float4* cb = colbuf + c0 + lane;

    float lh[R];
    if (nst > 0) {
        float S[R];
#pragma unroll
        for (int r = 0; r < R; ++r) S[r] = 0.0f;
#pragma unroll 4
        for (int s = 0; s < nst; ++s) {
            float4 yb = cb[s << 6];
#pragma unroll
            for (int r = 0; r < R; ++r) {
                float t = fmaf(x0[r], yb.x, fmaf(x1[r], yb.y, fmaf(x2[r], yb.z, yb.w)));
                S[r] += exp2fast(t - L[r]);
            }
        }
        float Ssum[R];
        bool redo = false;
#pragma unroll
        for (int r = 0; r < R; ++r) {
            Ssum[r] = wsum(S[r]);
            redo |= !(Ssum[r] >= 1e-19f && Ssum[r] <= 1e19f);  // 0/inf/NaN/drift
        }
        if (redo) {    // wave-uniform exact two-pass recompute
            float Mn[R];
#pragma unroll
            for (int r = 0; r < R; ++r) Mn[r] = -3.0e38f;
            for (int s = 0; s < nst; ++s) {
                float4 yb = cb[s << 6];
#pragma unroll
                for (int r = 0; r < R; ++r) {
                    float t = fmaf(x0[r], yb.x, fmaf(x1[r], yb.y, fmaf(x2[r], yb.z, yb.w)));
                    Mn[r] = fmaxf(Mn[r], t);
                }
            }
#pragma unroll
            for (int r = 0; r < R; ++r) { L[r] = wmax(Mn[r]); S[r] = 0.0f; }
            for (int s = 0; s < nst; ++s) {
                float4 yb = cb[s << 6];
#pragma unroll
                for (int r = 0; r < R; ++r) {
                    float t = fmaf(x0[r], yb.x, fmaf(x1[r], yb.y, fmaf(x2[r], yb.z, yb.w)));
                    S[r] += exp2fast(t - L[r]);
                }
            }
#pragma unroll
            for (int r = 0; r < R; ++r) Ssum[r] = wsum(S[r]);
        }
#pragma unroll
        for (int r = 0; r < R; ++r) {
            lh[r] = L[r] + log2fast(Ssum[r]);   // this half's LSE2
            L[r]  = lh[r];                      // persistent reference for next iter
        }
    } else {
#pragma unroll
        for (int r = 0; r < R; ++r) lh[r] = -1.0e38f;  // empty half (ncols <= c0)
    }

    if (lane == 0) {
#pragma unroll
        for (int r = 0; r < R; ++r) scratch[(wv << 2) + r].w = lh[r];
    }
    __syncthreads();
    if (h == 0) {   // merge halves, write f/g
        float fv[R];
#pragma unroll
        for (int r = 0; r < R; ++r) {
            float lo = lh[r];
            float po = scratch[(((wv ^ 8) << 2) + r)].w;
            float mx = fmaxf(lo, po);
            float tot = mx + log2fast(exp2fast(lo - mx) + exp2fast(po - mx));
            fv[r] = fmaf(-EPS_LN2, ar[r] + tot, eln);
        }
        float v = fv[0];
#pragma unroll
        for (int r = 1; r < R; ++r) v = (lane == r) ? fv[r] : v;
        if (lane < R && (r0 + lane) < nrows) outv[r0 + lane] = v;
    }
}

__launch_bounds__(TPB, 8)
__global__ void pcl_kernel(const float* __restrict__ pred,
                           const float* __restrict__ gt,
                           const int* __restrict__ nlen,
                           const int* __restrict__ mlen,
                           int* __restrict__ hdr,     // cnt[8], gen[8], done
                           float* __restrict__ fbuf,
                           float* __restrict__ gbuf,
                           float* __restrict__ parts,
                           float* __restrict__ bres,
                           float* __restrict__ out)
{
    __shared__ float4 xbuf[NPTS];   // (2k*x, v/scratch) : 32 KB
    __shared__ float4 ybuf[NPTS];   // (2k*y, u/scratch) : 32 KB

    const int tid  = threadIdx.x;
    const int wg   = blockIdx.x;
    const int b    = wg / WGB;
    const int wloc = wg % WGB;
    const int wv   = tid >> 6;       // 0..15
    const int lane = tid & 63;
    const int h    = wv >> 3;        // column half 0/1
    const int c0   = h * HALF;
    const int rg   = wloc * 8 + (wv & 7);  // row-group 0..511 within batch
    const int r0   = rg * R;
    const int n = nlen[b];
    const int m = mlen[b];
    const float nf = (float)n, mf = (float)m;
    const float* predb = pred + (size_t)b * NPTS * 3;
    const float* gtb   = gt   + (size_t)b * NPTS * 3;
    float* fb = fbuf + b * NPTS;
    float* gb = gbuf + b * NPTS;
    int* cnt = hdr + b;
    int* gen = hdr + 8 + b;
    int* done = hdr + 16;

    // stage scaled clipped clouds into LDS (own WG only -> no cross-WG dep)
    for (int idx = tid; idx < NPTS; idx += TPB) {
        const float* p = predb + (size_t)idx * 3;
        xbuf[idx] = make_float4(clipf(p[0]) * TWO_K, clipf(p[1]) * TWO_K, clipf(p[2]) * TWO_K, 0.0f);
        const float* q = gtb + (size_t)idx * 3;
        ybuf[idx] = make_float4(clipf(q[0]) * TWO_K, clipf(q[1]) * TWO_K, clipf(q[2]) * TWO_K, 0.0f);
    }

    const float eln_m = EPSV * LN2 * log2fast(mf);   // eps*ln(m)
    const float eln_n = EPSV * LN2 * log2fast(nf);   // eps*ln(n)

    // hoist this wave's row data (constant all 50 iterations)
    float px0[R], px1[R], px2[R], pxx[R], pax[R];
    float qy0[R], qy1[R], qy2[R], qyy[R], qay[R];
#pragma unroll
    for (int r = 0; r < R; ++r) {
        const float* p = predb + (size_t)(r0 + r) * 3;
        float a = clipf(p[0]), bq = clipf(p[1]), cq = clipf(p[2]);
        px0[r] = a; px1[r] = bq; px2[r] = cq;
        pxx[r] = fmaf(a, a, fmaf(bq, bq, cq * cq));
        pax[r] = -pxx[r] * KLOG2E;
        const float* q = gtb + (size_t)(r0 + r) * 3;
        float a2 = clipf(q[0]), b2 = clipf(q[1]), c2 = clipf(q[2]);
        qy0[r] = a2; qy1[r] = b2; qy2[r] = c2;
        qyy[r] = fmaf(a2, a2, fmaf(b2, b2, c2 * c2));
        qay[r] = -qyy[r] * KLOG2E;
    }
    float Lf[R], Lg[R];
#pragma unroll
    for (int r = 0; r < R; ++r) { Lf[r] = 3.0e38f; Lg[r] = 3.0e38f; }  // force exact redo at iter 0

    for (int it = 0; it < ITERS; ++it) {
        // u-phase: ybuf.w = k*(g - yy); iter 0 uses g == 0 (no gbuf init barrier needed)
        for (int j = tid; j < NPTS; j += TPB) {
            float4 yb = ybuf[j];
            float yy = fmaf(yb.x, yb.x, fmaf(yb.y, yb.y, yb.z * yb.z)) * INV_2K_SQ;
            float gval = (it == 0) ? 0.0f : gb[j];
            ybuf[j].w = (j < m) ? (gval - yy) * KLOG2E : NEGU;
        }
        __syncthreads();
        half_fused(ybuf, xbuf, px0, px1, px2, pax, fb, Lf, n, m, eln_m, r0, lane, wv, h, c0);
        batch_barrier(cnt, gen, tid);     // publish fb batch-wide
        // v-phase: xbuf.w = k*(f - xx)
        for (int i = tid; i < NPTS; i += TPB) {
            float4 xb = xbuf[i];
            float xx = fmaf(xb.x, xb.x, fmaf(xb.y, xb.y, xb.z * xb.z)) * INV_2K_SQ;
            xbuf[i].w = (i < n) ? (fb[i] - xx) * KLOG2E : NEGU;
        }
        __syncthreads();
        half_fused(xbuf, ybuf, qy0, qy1, qy2, qay, gb, Lg, m, n, eln_n, r0, lane, wv, h, c0);
        batch_barrier(cnt, gen, tid);     // publish gb batch-wide
    }

    // refresh u with final g for the cost pass
    for (int j = tid; j < NPTS; j += TPB) {
        float4 yb = ybuf[j];
        float yy = fmaf(yb.x, yb.x, fmaf(yb.y, yb.y, yb.z * yb.z)) * INV_2K_SQ;
        ybuf[j].w = (j < m) ? (gb[j] - yy) * KLOG2E : NEGU;
    }
    __syncthreads();

    // ---- pass A: transport cost + chamfer x->y (column-split) ----
    float wcost = 0.0f, chx = 0.0f;
    {
        float hrow[R], dmn[R];
#pragma unroll
        for (int r = 0; r < R; ++r) {
            hrow[r] = (r0 + r < n) ? (fb[r0 + r] - pxx[r]) * KLOG2E : NEGU;
            dmn[r] = BIGD;
        }
        const int ce  = min(m, c0 + HALF);
        const int nst = (ce > c0) ? ((ce - c0 + 63) >> 6) : 0;
        for (int s = 0; s < nst; ++s) {
            int jj = c0 + (s << 6) + lane;
            float4 yb = ybuf[jj];
            float yy = fmaf(yb.x, yb.x, fmaf(yb.y, yb.y, yb.z * yb.z)) * INV_2K_SQ;
            bool jv = jj < m;
#pragma unroll
            for (int r = 0; r < R; ++r) {
                float dots = fmaf(px0[r], yb.x, fmaf(px1[r], yb.y, px2[r] * yb.z));
                float e = hrow[r] + yb.w + dots;                  // k*(f+g-C)
                float w = exp2fast(e);                            // n*m*P_ij
                float C = fmaxf(fmaf(dots, -INV_K, pxx[r] + yy), 0.0f);
                wcost = fmaf(w, C, wcost);
                dmn[r] = fminf(dmn[r], jv ? C : BIGD);
            }
        }
#pragma unroll
        for (int r = 0; r < R; ++r) {
            float d = wmin(dmn[r]);
            if (lane == 0) xbuf[(wv << 2) + r].w = d;   // scratch for pair merge
            dmn[r] = d;
        }
        __syncthreads();
        if (h == 0) {
#pragma unroll
            for (int r = 0; r < R; ++r) {
                float d2 = fminf(dmn[r], xbuf[(((wv ^ 8) << 2) + r)].w);
                if (r0 + r < n) chx += d2;
            }
        }
        wcost = wsum(wcost);
    }
    __syncthreads();   // pass A's ybuf reads done before pass B scribbles ybuf.w

    // ---- pass B: chamfer y->x (column-split over n) ----
    float chy = 0.0f;
    {
        float dmn[R];
#pragma unroll
        for (int r = 0; r < R; ++r) dmn[r] = BIGD;
        const int ce  = min(n, c0 + HALF);
        const int nst = (ce > c0) ? ((ce - c0 + 63) >> 6) : 0;
        for (int s = 0; s < nst; ++s) {
            int ii = c0 + (s << 6) + lane;
            float4 xb = xbuf[ii];
            float xx = fmaf(xb.x, xb.x, fmaf(xb.y, xb.y, xb.z * xb.z)) * INV_2K_SQ;
            bool iv = ii < n;
#pragma unroll
            for (int r = 0; r < R; ++r) {
                float dots = fmaf(qy0[r], xb.x, fmaf(qy1[r], xb.y, qy2[r] * xb.z));
                float C = fmaxf(fmaf(dots, -INV_K, qyy[r] + xx), 0.0f);
                dmn[r] = fminf(dmn[r], iv ? C : BIGD);
            }
        }
#pragma unroll
        for (int r = 0; r < R; ++r) {
            float d = wmin(dmn[r]);
            if (lane == 0) ybuf[(wv << 2) + r].w = d;
            dmn[r] = d;
        }
        __syncthreads();
        if (h == 0) {
#pragma unroll
            for (int r = 0; r < R; ++r) {
                float d2 = fminf(dmn[r], ybuf[(((wv ^ 8) << 2) + r)].w);
                if (r0 + r < m) chy += d2;
            }
        }
    }
    __syncthreads();

    // ---- WG reduce (wcost, chx, chy) via xbuf-as-float scratch ----
    float* xs = (float*)xbuf;
    if (lane == 0) { xs[wv] = wcost; xs[16 + wv] = chx; xs[32 + wv] = chy; }
    __syncthreads();
    if (tid == 0) {
        float cs = 0.0f, cx = 0.0f, cy = 0.0f;
        for (int w = 0; w < 16; ++w) { cs += xs[w]; cx += xs[16 + w]; cy += xs[32 + w]; }
        parts[wg * 4 + 0] = cs;
        parts[wg * 4 + 1] = cx;
        parts[wg * 4 + 2] = cy;
    }
    batch_barrier(cnt, gen, tid);

    // ---- batch leader reduces 64 WGs (one per lane), then last batch finishes ----
    if (wloc == 0 && wv == 0) {
        float cs = parts[(b * WGB + lane) * 4 + 0];
        float cx = parts[(b * WGB + lane) * 4 + 1];
        float cy = parts[(b * WGB + lane) * 4 + 2];
        cs = wsum(cs); cx = wsum(cx); cy = wsum(cy);
        if (lane == 0) {
            float cost = cs / (nf * mf);
            bres[b] = sqrtf(fmaxf(cost, 0.0f)) + cx / nf + cy / mf;
            __threadfence();
            int a = __hip_atomic_fetch_add(done, 1, __ATOMIC_ACQ_REL, __HIP_MEMORY_SCOPE_AGENT);
            if (a == BATCH - 1) {
                float acc = 0.0f;
                for (int i2 = 0; i2 < BATCH; ++i2) acc += bres[i2];
                out[0] = acc * 0.125f;
            }
        }
    }
}

extern "C" void kernel_launch(void* const* d_in, const int* in_sizes, int n_in,
                              void* d_out, int out_size, void* d_ws, size_t ws_size,
                              hipStream_t stream) {
    const float* pred = (const float*)d_in[0];
    const float* gt   = (const float*)d_in[1];
    const int*  nlen  = (const int*)d_in[2];
    const int*  mlen  = (const int*)d_in[3];

    int*   hdr   = (int*)d_ws;            // cnt[8], gen[8], done, pad -> 32 ints
    float* base  = (float*)d_ws + 32;
    float* fbuf  = base;                  // 8*2048
    float* gbuf  = fbuf + BATCH * NPTS;   // 8*2048
    float* parts = gbuf + BATCH * NPTS;   // 512*4
    float* bres  = parts + NWG * 4;       // 8
    float* out   = (float*)d_out;

    hipMemsetAsync(d_ws, 0, 32 * sizeof(int), stream);   // zero barrier state each call
    hipLaunchKernelGGL(pcl_kernel, dim3(NWG), dim3(TPB), 0, stream,
                       pred, gt, nlen, mlen, hdr, fbuf, gbuf, parts, bres, out);
}

// Round 4
// 4911.042 us; speedup vs baseline: 1.8090x; 1.8090x over previous
//
#include <hip/hip_runtime.h>

#define BATCH 8
#define NPTS  2048
#define TPB   1024
#define WGB   64            // workgroups per batch
#define NWG   (BATCH*WGB)   // 512 = 2 per CU (64 KB LDS each, 160 KB/CU)
#define ITERS 50
#define R     4

#define KLOG2E    1442.6950408889634f    // log2(e)/eps
#define TWO_K     2885.3900817779268f    // 2*log2(e)/eps
#define INV_TK    3.4657359027997264e-4f // 1/(2k)
#define INV_K     6.931471805599453e-4f  // eps*ln2 = 1/KLOG2E
#define INV_2K_SQ 1.2011325347955035e-7f // 1/(2k)^2
#define AR_SCALE  -1.7328679513998632e-4f// -KLOG2E/(2k)^2 = -1/(4k)
#define EPS_LN2   6.931471805599453e-4f  // eps*ln2
#define LN2       0.6931471805599453f
#define EPSV      1e-3f
#define NEGU      -1e30f
#define BIGD      1e10f

__device__ __forceinline__ float exp2fast(float x) { return __builtin_amdgcn_exp2f(x); }
__device__ __forceinline__ float log2fast(float x) { return __builtin_amdgcn_logf(x); }
__device__ __forceinline__ float clipf(float v)    { return fminf(fmaxf(v, -1.0f), 1.0f); }

__device__ __forceinline__ float wsum(float v) {
#pragma unroll
    for (int d = 1; d < 64; d <<= 1) v += __shfl_xor(v, d);
    return v;
}
__device__ __forceinline__ float wmax(float v) {
#pragma unroll
    for (int d = 1; d < 64; d <<= 1) v = fmaxf(v, __shfl_xor(v, d));
    return v;
}
__device__ __forceinline__ float wmin(float v) {
#pragma unroll
    for (int d = 1; d < 64; d <<= 1) v = fminf(v, __shfl_xor(v, d));
    return v;
}

// Sense-reversing per-batch barrier over WGB workgroups (all resident by
// construction: __launch_bounds__(1024,8) guarantees 2 WG/CU, grid = 512).
__device__ __forceinline__ void batch_barrier(int* cnt, int* gen, int tid)
{
    __syncthreads();
    if (tid == 0) {
        __threadfence();                   // agent scope: publish WG's global writes
        int g = __hip_atomic_load(gen, __ATOMIC_RELAXED, __HIP_MEMORY_SCOPE_AGENT);
        int a = __hip_atomic_fetch_add(cnt, 1, __ATOMIC_ACQ_REL, __HIP_MEMORY_SCOPE_AGENT);
        if (a == WGB - 1) {
            __hip_atomic_store(cnt, 0, __ATOMIC_RELAXED, __HIP_MEMORY_SCOPE_AGENT);
            __hip_atomic_store(gen, g + 1, __ATOMIC_RELEASE, __HIP_MEMORY_SCOPE_AGENT);
        } else {
            while (__hip_atomic_load(gen, __ATOMIC_ACQUIRE, __HIP_MEMORY_SCOPE_AGENT) == g)
                __builtin_amdgcn_s_sleep(2);
        }
    }
    __syncthreads();
}

// One half-iteration over this wave's column half for R rows. Row fragments are
// re-derived from rowbuf LDS each call (no persistent registers -> no spill).
// Persistent per-row log2 reference L[]; exact two-pass redo on seed/drift.
// Pair (wv, wv^8) merges half-LSEs through rowbuf[0..63].w (rewritten by the
// next phase; .w writes never collide with .x/.y/.z reads - distinct dwords).
__device__ __forceinline__ void half_fused(const float4* __restrict__ colbuf,
                                           float4* __restrict__ rowbuf,
                                           float* __restrict__ outv, float* L,
                                           int nrows, int ncols, float eln,
                                           int r0, int lane, int wv, int h)
{
    const int ph  = ((ncols + 127) >> 7) << 6;   // balanced split, multiple of 64
    const int c0  = h ? ph : 0;
    const int ce  = h ? ncols : ph;
    const int nst = (ce - c0 + 63) >> 6;
    const float4* cb = colbuf + c0 + lane;

    float x0[R], x1[R], x2[R], ar[R];
#pragma unroll
    for (int r = 0; r < R; ++r) {
        float4 s = rowbuf[r0 + r];               // broadcast read (scaled 2k*x)
        x0[r] = s.x * INV_TK; x1[r] = s.y * INV_TK; x2[r] = s.z * INV_TK;
        ar[r] = AR_SCALE * fmaf(s.x, s.x, fmaf(s.y, s.y, s.z * s.z));  // -k*xx
    }

    float lh[R];
    if (nst > 0) {
        float S[R];
#pragma unroll
        for (int r = 0; r < R; ++r) S[r] = 0.0f;
#pragma unroll 2
        for (int s = 0; s < nst; ++s) {
            float4 yb = cb[s << 6];
#pragma unroll
            for (int r = 0; r < R; ++r) {
                float t = fmaf(x0[r], yb.x, fmaf(x1[r], yb.y, fmaf(x2[r], yb.z, yb.w)));
                S[r] += exp2fast(t - L[r]);
            }
        }
        float Ssum[R];
        bool redo = false;
#pragma unroll
        for (int r = 0; r < R; ++r) {
            Ssum[r] = wsum(S[r]);
            redo |= !(Ssum[r] >= 1e-19f && Ssum[r] <= 1e19f);  // 0/inf/NaN/drift
        }
        if (redo) {   // wave-uniform exact two-pass recompute
            float Mn[R];
#pragma unroll
            for (int r = 0; r < R; ++r) Mn[r] = -3.0e38f;
            for (int s = 0; s < nst; ++s) {
                float4 yb = cb[s << 6];
#pragma unroll
                for (int r = 0; r < R; ++r) {
                    float t = fmaf(x0[r], yb.x, fmaf(x1[r], yb.y, fmaf(x2[r], yb.z, yb.w)));
                    Mn[r] = fmaxf(Mn[r], t);
                }
            }
#pragma unroll
            for (int r = 0; r < R; ++r) { L[r] = wmax(Mn[r]); S[r] = 0.0f; }
            for (int s = 0; s < nst; ++s) {
                float4 yb = cb[s << 6];
#pragma unroll
                for (int r = 0; r < R; ++r) {
                    float t = fmaf(x0[r], yb.x, fmaf(x1[r], yb.y, fmaf(x2[r], yb.z, yb.w)));
                    S[r] += exp2fast(t - L[r]);
                }
            }
#pragma unroll
            for (int r = 0; r < R; ++r) Ssum[r] = wsum(S[r]);
        }
#pragma unroll
        for (int r = 0; r < R; ++r) {
            lh[r] = L[r] + log2fast(Ssum[r]);   // this half's LSE2
            L[r]  = lh[r];                      // persistent reference
        }
    } else {
#pragma unroll
        for (int r = 0; r < R; ++r) lh[r] = -1.0e38f;
    }

    if (lane == 0) {
#pragma unroll
        for (int r = 0; r < R; ++r) rowbuf[(wv << 2) + r].w = lh[r];
    }
    __syncthreads();
    if (h == 0) {   // merge halves, write f/g
#pragma unroll
        for (int r = 0; r < R; ++r) {
            float lo = lh[r];
            float po = rowbuf[(((wv ^ 8) << 2) + r)].w;
            float mx = fmaxf(lo, po);
            float tot = mx + log2fast(exp2fast(lo - mx) + exp2fast(po - mx));
            float fv = fmaf(-EPS_LN2, ar[r] + tot, eln);
            if (lane == 0 && (r0 + r) < nrows) outv[r0 + r] = fv;
        }
    }
}

__launch_bounds__(TPB, 8)
__global__ void pcl_kernel(const float* __restrict__ pred,
                           const float* __restrict__ gt,
                           const int* __restrict__ nlen,
                           const int* __restrict__ mlen,
                           int* __restrict__ hdr,
                           float* __restrict__ fbuf,
                           float* __restrict__ gbuf,
                           float* __restrict__ parts,
                           float* __restrict__ bres,
                           float* __restrict__ out)
{
    __shared__ float4 xbuf[NPTS];   // (2k*x, v/scratch) : 32 KB
    __shared__ float4 ybuf[NPTS];   // (2k*y, u/scratch) : 32 KB

    const int tid  = threadIdx.x;
    const int wg   = blockIdx.x;
    const int b    = wg / WGB;
    const int wloc = wg % WGB;
    const int wv   = tid >> 6;       // 0..15
    const int lane = tid & 63;
    const int h    = wv >> 3;        // column half 0/1
    const int rg   = wloc * 8 + (wv & 7);  // row-group 0..511 within batch
    const int r0   = rg * R;
    const int n = nlen[b];
    const int m = mlen[b];
    const float nf = (float)n, mf = (float)m;
    const float* predb = pred + (size_t)b * NPTS * 3;
    const float* gtb   = gt   + (size_t)b * NPTS * 3;
    float* fb = fbuf + b * NPTS;
    float* gb = gbuf + b * NPTS;
    int* cnt  = hdr + b * 16;        // 64 B apart: no cross-batch line sharing
    int* gen  = hdr + 128 + b * 16;
    int* done = hdr + 256;

    // stage scaled clipped clouds into LDS
    for (int idx = tid; idx < NPTS; idx += TPB) {
        const float* p = predb + (size_t)idx * 3;
        xbuf[idx] = make_float4(clipf(p[0]) * TWO_K, clipf(p[1]) * TWO_K, clipf(p[2]) * TWO_K, 0.0f);
        const float* q = gtb + (size_t)idx * 3;
        ybuf[idx] = make_float4(clipf(q[0]) * TWO_K, clipf(q[1]) * TWO_K, clipf(q[2]) * TWO_K, 0.0f);
    }

    const float eln_m = EPSV * LN2 * log2fast(mf);   // eps*ln(m)
    const float eln_n = EPSV * LN2 * log2fast(nf);   // eps*ln(n)

    float Lf[R], Lg[R];
#pragma unroll
    for (int r = 0; r < R; ++r) { Lf[r] = 3.0e38f; Lg[r] = 3.0e38f; }  // force exact redo at iter 0

    for (int it = 0; it < ITERS; ++it) {
        // u-phase: ybuf.w = k*(g - yy); iter 0 uses g == 0
        for (int j = tid; j < NPTS; j += TPB) {
            float4 yb = ybuf[j];
            float yy = fmaf(yb.x, yb.x, fmaf(yb.y, yb.y, yb.z * yb.z)) * INV_2K_SQ;
            float gval = (it == 0) ? 0.0f : gb[j];
            ybuf[j].w = (j < m) ? (gval - yy) * KLOG2E : NEGU;
        }
        __syncthreads();
        half_fused(ybuf, xbuf, fb, Lf, n, m, eln_m, r0, lane, wv, h);   // f = update(g)
        batch_barrier(cnt, gen, tid);
        // v-phase: xbuf.w = k*(f - xx)
        for (int i = tid; i < NPTS; i += TPB) {
            float4 xb = xbuf[i];
            float xx = fmaf(xb.x, xb.x, fmaf(xb.y, xb.y, xb.z * xb.z)) * INV_2K_SQ;
            xbuf[i].w = (i < n) ? (fb[i] - xx) * KLOG2E : NEGU;
        }
        __syncthreads();
        half_fused(xbuf, ybuf, gb, Lg, m, n, eln_n, r0, lane, wv, h);   // g = update(f)
        batch_barrier(cnt, gen, tid);
    }

    // refresh u with final g for the cost pass
    for (int j = tid; j < NPTS; j += TPB) {
        float4 yb = ybuf[j];
        float yy = fmaf(yb.x, yb.x, fmaf(yb.y, yb.y, yb.z * yb.z)) * INV_2K_SQ;
        ybuf[j].w = (j < m) ? (gb[j] - yy) * KLOG2E : NEGU;
    }
    __syncthreads();

    // ---- pass A: transport cost + chamfer x->y (dynamic column split over m) ----
    float wcost = 0.0f, chx = 0.0f;
    {
        float px0[R], px1[R], px2[R], pxx[R], hrow[R], dmn[R];
#pragma unroll
        for (int r = 0; r < R; ++r) {
            float4 s = xbuf[r0 + r];
            px0[r] = s.x * INV_TK; px1[r] = s.y * INV_TK; px2[r] = s.z * INV_TK;
            pxx[r] = fmaf(s.x, s.x, fmaf(s.y, s.y, s.z * s.z)) * INV_2K_SQ;
            hrow[r] = (r0 + r < n) ? (fb[r0 + r] - pxx[r]) * KLOG2E : NEGU;
            dmn[r] = BIGD;
        }
        const int ph  = ((m + 127) >> 7) << 6;
        const int c0  = h ? ph : 0;
        const int ce  = h ? m : ph;
        const int nst = (ce - c0 + 63) >> 6;
#pragma unroll 2
        for (int s = 0; s < nst; ++s) {
            int jj = c0 + (s << 6) + lane;
            float4 yb = ybuf[jj];
            float yy = fmaf(yb.x, yb.x, fmaf(yb.y, yb.y, yb.z * yb.z)) * INV_2K_SQ;
            bool jv = jj < m;
#pragma unroll
            for (int r = 0; r < R; ++r) {
                float dots = fmaf(px0[r], yb.x, fmaf(px1[r], yb.y, px2[r] * yb.z)); // 2k*(x.y)
                float e = hrow[r] + yb.w + dots;                  // k*(f+g-C)
                float w = exp2fast(e);                            // n*m*P_ij
                float C = fmaxf(fmaf(dots, -INV_K, pxx[r] + yy), 0.0f);
                wcost = fmaf(w, C, wcost);
                dmn[r] = fminf(dmn[r], jv ? C : BIGD);
            }
        }
#pragma unroll
        for (int r = 0; r < R; ++r) {
            float d = wmin(dmn[r]);
            if (lane == 0) xbuf[(wv << 2) + r].w = d;
            dmn[r] = d;
        }
        __syncthreads();
        if (h == 0) {
#pragma unroll
            for (int r = 0; r < R; ++r) {
                float d2 = fminf(dmn[r], xbuf[(((wv ^ 8) << 2) + r)].w);
                if (r0 + r < n) chx += d2;
            }
        }
        wcost = wsum(wcost);
    }
    __syncthreads();

    // ---- pass B: chamfer y->x (dynamic column split over n) ----
    float chy = 0.0f;
    {
        float qy0[R], qy1[R], qy2[R], qyy[R], dmn[R];
#pragma unroll
        for (int r = 0; r < R; ++r) {
            float4 s = ybuf[r0 + r];
            qy0[r] = s.x * INV_TK; qy1[r] = s.y * INV_TK; qy2[r] = s.z * INV_TK;
            qyy[r] = fmaf(s.x, s.x, fmaf(s.y, s.y, s.z * s.z)) * INV_2K_SQ;
            dmn[r] = BIGD;
        }
        const int ph  = ((n + 127) >> 7) << 6;
        const int c0  = h ? ph : 0;
        const int ce  = h ? n : ph;
        const int nst = (ce - c0 + 63) >> 6;
#pragma unroll 2
        for (int s = 0; s < nst; ++s) {
            int ii = c0 + (s << 6) + lane;
            float4 xb = xbuf[ii];
            float xx = fmaf(xb.x, xb.x, fmaf(xb.y, xb.y, xb.z * xb.z)) * INV_2K_SQ;
            bool iv = ii < n;
#pragma unroll
            for (int r = 0; r < R; ++r) {
                float dots = fmaf(qy0[r], xb.x, fmaf(qy1[r], xb.y, qy2[r] * xb.z));
                float C = fmaxf(fmaf(dots, -INV_K, qyy[r] + xx), 0.0f);
                dmn[r] = fminf(dmn[r], iv ? C : BIGD);
            }
        }
#pragma unroll
        for (int r = 0; r < R; ++r) {
            float d = wmin(dmn[r]);
            if (lane == 0) ybuf[(wv << 2) + r].w = d;
            dmn[r] = d;
        }
        __syncthreads();
        if (h == 0) {
#pragma unroll
            for (int r = 0; r < R; ++r) {
                float d2 = fminf(dmn[r], ybuf[(((wv ^ 8) << 2) + r)].w);
                if (r0 + r < m) chy += d2;
            }
        }
    }
    __syncthreads();

    // ---- WG reduce via xbuf-as-float scratch ----
    float* xs = (float*)xbuf;
    if (lane == 0) { xs[wv] = wcost; xs[16 + wv] = chx; xs[32 + wv] = chy; }
    __syncthreads();
    if (tid == 0) {
        float cs = 0.0f, cx = 0.0f, cy = 0.0f;
        for (int w = 0; w < 16; ++w) { cs += xs[w]; cx += xs[16 + w]; cy += xs[32 + w]; }
        parts[wg * 4 + 0] = cs;
        parts[wg * 4 + 1] = cx;
        parts[wg * 4 + 2] = cy;
    }
    batch_barrier(cnt, gen, tid);

    // ---- batch leader reduces its 64 WGs (one per lane); last batch finishes ----
    if (wloc == 0 && wv == 0) {
        float cs = parts[(b * WGB + lane) * 4 + 0];
        float cx = parts[(b * WGB + lane) * 4 + 1];
        float cy = parts[(b * WGB + lane) * 4 + 2];
        cs = wsum(cs); cx = wsum(cx); cy = wsum(cy);
        if (lane == 0) {
            float cost = cs / (nf * mf);
            bres[b] = sqrtf(fmaxf(cost, 0.0f)) + cx / nf + cy / mf;
            __threadfence();
            int a = __hip_atomic_fetch_add(done, 1, __ATOMIC_ACQ_REL, __HIP_MEMORY_SCOPE_AGENT);
            if (a == BATCH - 1) {
                float acc = 0.0f;
                for (int i2 = 0; i2 < BATCH; ++i2) acc += bres[i2];
                out[0] = acc * 0.125f;
            }
        }
    }
}

extern "C" void kernel_launch(void* const* d_in, const int* in_sizes, int n_in,
                              void* d_out, int out_size, void* d_ws, size_t ws_size,
                              hipStream_t stream) {
    const float* pred = (const float*)d_in[0];
    const float* gt   = (const float*)d_in[1];
    const int*  nlen  = (const int*)d_in[2];
    const int*  mlen  = (const int*)d_in[3];

    int*   hdr   = (int*)d_ws;            // cnt[b] at b*16, gen[b] at 128+b*16, done at 256
    float* base  = (float*)d_ws + 512;    // skip 2048 B of barrier state
    float* fbuf  = base;                  // 8*2048
    float* gbuf  = fbuf + BATCH * NPTS;   // 8*2048
    float* parts = gbuf + BATCH * NPTS;   // 512*4
    float* bres  = parts + NWG * 4;       // 8
    float* out   = (float*)d_out;

    hipMemsetAsync(d_ws, 0, 2048, stream);   // zero barrier state each call
    hipLaunchKernelGGL(pcl_kernel, dim3(NWG), dim3(TPB), 0, stream,
                       pred, gt, nlen, mlen, hdr, fbuf, gbuf, parts, bres, out);
}

// Round 5
// 3375.521 us; speedup vs baseline: 2.6318x; 1.4549x over previous
//
#include <hip/hip_runtime.h>

#define BATCH 8
#define NPTS  2048
#define TPB   512           // 8 waves/WG -> 2 WG/CU -> 4 waves/SIMD -> 128 VGPR budget
#define WGB   64            // workgroups per batch
#define NWG   (BATCH*WGB)   // 512 = 2 per CU (LDS-limited: 2 x 64 KB <= 160 KB)
#define ITERS 50
#define R     4

#define KLOG2E    1442.6950408889634f    // log2(e)/eps
#define TWO_K     2885.3900817779268f    // 2*log2(e)/eps
#define INV_TK    3.4657359027997264e-4f // 1/(2k)
#define INV_K     6.931471805599453e-4f  // eps*ln2 = 1/KLOG2E
#define INV_2K_SQ 1.2011325347955035e-7f // 1/(2k)^2
#define AR_SCALE  -1.7328679513998632e-4f// -1/(4k)  (= -k/(2k)^2)
#define EPS_LN2   6.931471805599453e-4f  // eps*ln2
#define LN2       0.6931471805599453f
#define EPSV      1e-3f
#define NEGU      -1e30f
#define BIGD      1e10f

__device__ __forceinline__ float exp2fast(float x) { return __builtin_amdgcn_exp2f(x); }
__device__ __forceinline__ float log2fast(float x) { return __builtin_amdgcn_logf(x); }
__device__ __forceinline__ float clipf(float v)    { return fminf(fmaxf(v, -1.0f), 1.0f); }

__device__ __forceinline__ float wsum(float v) {
#pragma unroll
    for (int d = 1; d < 64; d <<= 1) v += __shfl_xor(v, d);
    return v;
}
__device__ __forceinline__ float wmax(float v) {
#pragma unroll
    for (int d = 1; d < 64; d <<= 1) v = fmaxf(v, __shfl_xor(v, d));
    return v;
}
__device__ __forceinline__ float wmin(float v) {
#pragma unroll
    for (int d = 1; d < 64; d <<= 1) v = fminf(v, __shfl_xor(v, d));
    return v;
}

// Sense-reversing per-batch barrier over WGB workgroups (all resident:
// LDS limits to exactly 2 WG/CU and grid == 512 == capacity; VGPR stays
// well under the 128/wave budget of 4 waves/SIMD).
__device__ __forceinline__ void batch_barrier(int* cnt, int* gen, int tid)
{
    __syncthreads();
    if (tid == 0) {
        __threadfence();                   // agent scope: publish WG's global writes
        int g = __hip_atomic_load(gen, __ATOMIC_RELAXED, __HIP_MEMORY_SCOPE_AGENT);
        int a = __hip_atomic_fetch_add(cnt, 1, __ATOMIC_ACQ_REL, __HIP_MEMORY_SCOPE_AGENT);
        if (a == WGB - 1) {
            __hip_atomic_store(cnt, 0, __ATOMIC_RELAXED, __HIP_MEMORY_SCOPE_AGENT);
            __hip_atomic_store(gen, g + 1, __ATOMIC_RELEASE, __HIP_MEMORY_SCOPE_AGENT);
        } else {
            while (__hip_atomic_load(gen, __ATOMIC_ACQUIRE, __HIP_MEMORY_SCOPE_AGENT) == g)
                __builtin_amdgcn_s_sleep(2);
        }
    }
    __syncthreads();
}

// One half-iteration of log-domain Sinkhorn: this wave scans ALL columns for
// its R rows. Row fragments re-derived from rowbuf LDS (no persistent row
// registers). Persistent per-row log2 reference L[]; exact two-pass redo on
// seed (iter 0) / drift / NaN. No intra-call syncthreads.
__device__ __forceinline__ void half_fused(const float4* __restrict__ colbuf,
                                           const float4* __restrict__ rowbuf,
                                           float* __restrict__ outv, float* L,
                                           int nrows, int ncols, float eln,
                                           int r0, int lane)
{
    if (r0 >= nrows) return;
    const int nst = (ncols + 63) >> 6;
    const float4* cb = colbuf + lane;

    float x0[R], x1[R], x2[R], ar[R];
#pragma unroll
    for (int r = 0; r < R; ++r) {
        float4 s = rowbuf[r0 + r];               // broadcast read (scaled 2k*x)
        x0[r] = s.x * INV_TK; x1[r] = s.y * INV_TK; x2[r] = s.z * INV_TK;
        ar[r] = AR_SCALE * fmaf(s.x, s.x, fmaf(s.y, s.y, s.z * s.z));  // -k*xx
    }

    float S[R];
#pragma unroll
    for (int r = 0; r < R; ++r) S[r] = 0.0f;
#pragma unroll 2
    for (int s = 0; s < nst; ++s) {
        float4 yb = cb[s << 6];
#pragma unroll
        for (int r = 0; r < R; ++r) {
            float t = fmaf(x0[r], yb.x, fmaf(x1[r], yb.y, fmaf(x2[r], yb.z, yb.w)));
            S[r] += exp2fast(t - L[r]);
        }
    }
    float Ssum[R];
    bool redo = false;
#pragma unroll
    for (int r = 0; r < R; ++r) {
        Ssum[r] = wsum(S[r]);
        redo |= !(Ssum[r] >= 1e-19f && Ssum[r] <= 1e19f);  // 0/inf/NaN/drift
    }
    if (redo) {   // wave-uniform exact two-pass recompute
        float Mn[R];
#pragma unroll
        for (int r = 0; r < R; ++r) Mn[r] = -3.0e38f;
        for (int s = 0; s < nst; ++s) {
            float4 yb = cb[s << 6];
#pragma unroll
            for (int r = 0; r < R; ++r) {
                float t = fmaf(x0[r], yb.x, fmaf(x1[r], yb.y, fmaf(x2[r], yb.z, yb.w)));
                Mn[r] = fmaxf(Mn[r], t);
            }
        }
#pragma unroll
        for (int r = 0; r < R; ++r) { L[r] = wmax(Mn[r]); S[r] = 0.0f; }
        for (int s = 0; s < nst; ++s) {
            float4 yb = cb[s << 6];
#pragma unroll
            for (int r = 0; r < R; ++r) {
                float t = fmaf(x0[r], yb.x, fmaf(x1[r], yb.y, fmaf(x2[r], yb.z, yb.w)));
                S[r] += exp2fast(t - L[r]);
            }
        }
#pragma unroll
        for (int r = 0; r < R; ++r) Ssum[r] = wsum(S[r]);
    }

    float fv[R];
#pragma unroll
    for (int r = 0; r < R; ++r) {
        float lh = L[r] + log2fast(Ssum[r]);    // new LSE2
        L[r] = lh;                              // persistent reference
        fv[r] = fmaf(-EPS_LN2, ar[r] + lh, eln);
    }
    float v = fv[0];
#pragma unroll
    for (int r = 1; r < R; ++r) v = (lane == r) ? fv[r] : v;
    if (lane < R && (r0 + lane) < nrows) outv[r0 + lane] = v;
}

__launch_bounds__(TPB)
__global__ void pcl_kernel(const float* __restrict__ pred,
                           const float* __restrict__ gt,
                           const int* __restrict__ nlen,
                           const int* __restrict__ mlen,
                           int* __restrict__ hdr,
                           float* __restrict__ fbuf,
                           float* __restrict__ gbuf,
                           float* __restrict__ parts,
                           float* __restrict__ bres,
                           float* __restrict__ out)
{
    __shared__ float4 xbuf[NPTS];   // (2k*x, v) : 32 KB
    __shared__ float4 ybuf[NPTS];   // (2k*y, u) : 32 KB

    const int tid  = threadIdx.x;
    const int wg   = blockIdx.x;
    const int b    = wg / WGB;
    const int wloc = wg % WGB;
    const int wv   = tid >> 6;       // 0..7
    const int lane = tid & 63;
    const int r0   = wloc * 32 + wv * R;   // this wave's first row (0..2044)
    const int n = nlen[b];
    const int m = mlen[b];
    const float nf = (float)n, mf = (float)m;
    const float* predb = pred + (size_t)b * NPTS * 3;
    const float* gtb   = gt   + (size_t)b * NPTS * 3;
    float* fb = fbuf + b * NPTS;
    float* gb = gbuf + b * NPTS;
    int* cnt  = hdr + b * 16;        // 64 B apart: no cross-batch line sharing
    int* gen  = hdr + 128 + b * 16;
    int* done = hdr + 256;

    // stage scaled clipped clouds into LDS
    for (int idx = tid; idx < NPTS; idx += TPB) {
        const float* p = predb + (size_t)idx * 3;
        xbuf[idx] = make_float4(clipf(p[0]) * TWO_K, clipf(p[1]) * TWO_K, clipf(p[2]) * TWO_K, 0.0f);
        const float* q = gtb + (size_t)idx * 3;
        ybuf[idx] = make_float4(clipf(q[0]) * TWO_K, clipf(q[1]) * TWO_K, clipf(q[2]) * TWO_K, 0.0f);
    }

    const float eln_m = EPSV * LN2 * log2fast(mf);   // eps*ln(m)
    const float eln_n = EPSV * LN2 * log2fast(nf);   // eps*ln(n)

    float Lf[R], Lg[R];
#pragma unroll
    for (int r = 0; r < R; ++r) { Lf[r] = 3.0e38f; Lg[r] = 3.0e38f; }  // force exact redo at iter 0

    for (int it = 0; it < ITERS; ++it) {
        // u-phase: ybuf.w = k*(g - yy); iter 0 uses g == 0
        for (int j = tid; j < NPTS; j += TPB) {
            float4 yb = ybuf[j];
            float yy = fmaf(yb.x, yb.x, fmaf(yb.y, yb.y, yb.z * yb.z)) * INV_2K_SQ;
            float gval = (it == 0) ? 0.0f : gb[j];
            ybuf[j].w = (j < m) ? (gval - yy) * KLOG2E : NEGU;
        }
        __syncthreads();
        half_fused(ybuf, xbuf, fb, Lf, n, m, eln_m, r0, lane);   // f = update(g)
        batch_barrier(cnt, gen, tid);
        // v-phase: xbuf.w = k*(f - xx)
        for (int i = tid; i < NPTS; i += TPB) {
            float4 xb = xbuf[i];
            float xx = fmaf(xb.x, xb.x, fmaf(xb.y, xb.y, xb.z * xb.z)) * INV_2K_SQ;
            xbuf[i].w = (i < n) ? (fb[i] - xx) * KLOG2E : NEGU;
        }
        __syncthreads();
        half_fused(xbuf, ybuf, gb, Lg, m, n, eln_n, r0, lane);   // g = update(f)
        batch_barrier(cnt, gen, tid);
    }

    // refresh u with final g for the cost pass
    for (int j = tid; j < NPTS; j += TPB) {
        float4 yb = ybuf[j];
        float yy = fmaf(yb.x, yb.x, fmaf(yb.y, yb.y, yb.z * yb.z)) * INV_2K_SQ;
        ybuf[j].w = (j < m) ? (gb[j] - yy) * KLOG2E : NEGU;
    }
    __syncthreads();

    // ---- pass A: transport cost + chamfer x->y ----
    float wcost = 0.0f, chx = 0.0f;
    if (r0 < n) {
        float px0[R], px1[R], px2[R], pxx[R], hrow[R], dmn[R];
#pragma unroll
        for (int r = 0; r < R; ++r) {
            float4 s = xbuf[r0 + r];
            px0[r] = s.x * INV_TK; px1[r] = s.y * INV_TK; px2[r] = s.z * INV_TK;
            pxx[r] = fmaf(s.x, s.x, fmaf(s.y, s.y, s.z * s.z)) * INV_2K_SQ;
            hrow[r] = (r0 + r < n) ? (fb[r0 + r] - pxx[r]) * KLOG2E : NEGU;
            dmn[r] = BIGD;
        }
        const int nst = (m + 63) >> 6;
#pragma unroll 2
        for (int s = 0; s < nst; ++s) {
            int jj = (s << 6) + lane;
            float4 yb = ybuf[jj];
            float yy = fmaf(yb.x, yb.x, fmaf(yb.y, yb.y, yb.z * yb.z)) * INV_2K_SQ;
            bool jv = jj < m;
#pragma unroll
            for (int r = 0; r < R; ++r) {
                float dots = fmaf(px0[r], yb.x, fmaf(px1[r], yb.y, px2[r] * yb.z)); // 2k*(x.y)
                float e = hrow[r] + yb.w + dots;                  // k*(f+g-C)
                float w = exp2fast(e);                            // n*m*P_ij
                float C = fmaxf(fmaf(dots, -INV_K, pxx[r] + yy), 0.0f);
                wcost = fmaf(w, C, wcost);
                dmn[r] = fminf(dmn[r], jv ? C : BIGD);
            }
        }
#pragma unroll
        for (int r = 0; r < R; ++r) {
            float d = wmin(dmn[r]);
            if (r0 + r < n) chx += d;   // lane-uniform
        }
        wcost = wsum(wcost);
    }

    // ---- pass B: chamfer y->x ----
    float chy = 0.0f;
    if (r0 < m) {
        float qy0[R], qy1[R], qy2[R], qyy[R], dmn[R];
#pragma unroll
        for (int r = 0; r < R; ++r) {
            float4 s = ybuf[r0 + r];
            qy0[r] = s.x * INV_TK; qy1[r] = s.y * INV_TK; qy2[r] = s.z * INV_TK;
            qyy[r] = fmaf(s.x, s.x, fmaf(s.y, s.y, s.z * s.z)) * INV_2K_SQ;
            dmn[r] = BIGD;
        }
        const int nst = (n + 63) >> 6;
#pragma unroll 2
        for (int s = 0; s < nst; ++s) {
            int ii = (s << 6) + lane;
            float4 xb = xbuf[ii];
            float xx = fmaf(xb.x, xb.x, fmaf(xb.y, xb.y, xb.z * xb.z)) * INV_2K_SQ;
            bool iv = ii < n;
#pragma unroll
            for (int r = 0; r < R; ++r) {
                float dots = fmaf(qy0[r], xb.x, fmaf(qy1[r], xb.y, qy2[r] * xb.z));
                float C = fmaxf(fmaf(dots, -INV_K, qyy[r] + xx), 0.0f);
                dmn[r] = fminf(dmn[r], iv ? C : BIGD);
            }
        }
#pragma unroll
        for (int r = 0; r < R; ++r) {
            float d = wmin(dmn[r]);
            if (r0 + r < m) chy += d;
        }
    }
    __syncthreads();

    // ---- WG reduce via xbuf-as-float scratch ----
    float* xs = (float*)xbuf;
    if (lane == 0) { xs[wv] = wcost; xs[8 + wv] = chx; xs[16 + wv] = chy; }
    __syncthreads();
    if (tid == 0) {
        float cs = 0.0f, cx = 0.0f, cy = 0.0f;
        for (int w = 0; w < 8; ++w) { cs += xs[w]; cx += xs[8 + w]; cy += xs[16 + w]; }
        parts[wg * 4 + 0] = cs;
        parts[wg * 4 + 1] = cx;
        parts[wg * 4 + 2] = cy;
    }
    batch_barrier(cnt, gen, tid);

    // ---- batch leader reduces its 64 WGs (one per lane); last batch finishes ----
    if (wloc == 0 && wv == 0) {
        float cs = parts[(b * WGB + lane) * 4 + 0];
        float cx = parts[(b * WGB + lane) * 4 + 1];
        float cy = parts[(b * WGB + lane) * 4 + 2];
        cs = wsum(cs); cx = wsum(cx); cy = wsum(cy);
        if (lane == 0) {
            float cost = cs / (nf * mf);
            bres[b] = sqrtf(fmaxf(cost, 0.0f)) + cx / nf + cy / mf;
            __threadfence();
            int a = __hip_atomic_fetch_add(done, 1, __ATOMIC_ACQ_REL, __HIP_MEMORY_SCOPE_AGENT);
            if (a == BATCH - 1) {
                float acc = 0.0f;
                for (int i2 = 0; i2 < BATCH; ++i2) acc += bres[i2];
                out[0] = acc * 0.125f;
            }
        }
    }
}

extern "C" void kernel_launch(void* const* d_in, const int* in_sizes, int n_in,
                              void* d_out, int out_size, void* d_ws, size_t ws_size,
                              hipStream_t stream) {
    const float* pred = (const float*)d_in[0];
    const float* gt   = (const float*)d_in[1];
    const int*  nlen  = (const int*)d_in[2];
    const int*  mlen  = (const int*)d_in[3];

    int*   hdr   = (int*)d_ws;            // cnt[b] at b*16, gen[b] at 128+b*16, done at 256
    float* base  = (float*)d_ws + 512;    // skip 2048 B of barrier state
    float* fbuf  = base;                  // 8*2048
    float* gbuf  = fbuf + BATCH * NPTS;   // 8*2048
    float* parts = gbuf + BATCH * NPTS;   // 512*4
    float* bres  = parts + NWG * 4;       // 8
    float* out   = (float*)d_out;

    hipMemsetAsync(d_ws, 0, 2048, stream);   // zero barrier state each call
    hipLaunchKernelGGL(pcl_kernel, dim3(NWG), dim3(TPB), 0, stream,
                       pred, gt, nlen, mlen, hdr, fbuf, gbuf, parts, bres, out);
}

// Round 6
// 835.871 us; speedup vs baseline: 10.6282x; 4.0383x over previous
//
#include <hip/hip_runtime.h>

#define BATCH 8
#define NPTS  2048
#define TPB   512           // 8 waves/WG, 2 WG/CU (LDS: 2x64KB<=160KB), 4 waves/SIMD
#define WGB   64            // workgroups per batch
#define NWG   (BATCH*WGB)   // 512 = exact residency capacity
#define ITERS 50
#define R     4

#define KLOG2E    1442.6950408889634f    // log2(e)/eps
#define TWO_K     2885.3900817779268f    // 2*log2(e)/eps
#define INV_TK    3.4657359027997264e-4f // 1/(2k)
#define INV_K     6.931471805599453e-4f  // eps*ln2 = 1/KLOG2E
#define INV_2K_SQ 1.2011325347955035e-7f // 1/(2k)^2
#define AR_SCALE  -1.7328679513998632e-4f// -1/(4k)  (= -k/(2k)^2)
#define EPS_LN2   6.931471805599453e-4f  // eps*ln2
#define LN2       0.6931471805599453f
#define EPSV      1e-3f
#define NEGU      -1e30f
#define BIGD      1e10f

__device__ __forceinline__ float exp2fast(float x) { return __builtin_amdgcn_exp2f(x); }
__device__ __forceinline__ float log2fast(float x) { return __builtin_amdgcn_logf(x); }
__device__ __forceinline__ float clipf(float v)    { return fminf(fmaxf(v, -1.0f), 1.0f); }

// All cross-WG data goes through relaxed AGENT-scope atomics: coherent at the
// Infinity Cache (sc-flagged ops), no stale caching possible -> NO fences,
// NO L2 writeback/invalidate. Ordering via explicit s_waitcnt vmcnt(0).
__device__ __forceinline__ float aloadf(const float* p) {
    return __hip_atomic_load(p, __ATOMIC_RELAXED, __HIP_MEMORY_SCOPE_AGENT);
}
__device__ __forceinline__ void astoref(float* p, float v) {
    __hip_atomic_store(p, v, __ATOMIC_RELAXED, __HIP_MEMORY_SCOPE_AGENT);
}
__device__ __forceinline__ int aloadi(const int* p) {
    return __hip_atomic_load(p, __ATOMIC_RELAXED, __HIP_MEMORY_SCOPE_AGENT);
}

__device__ __forceinline__ float wsum(float v) {
#pragma unroll
    for (int d = 1; d < 64; d <<= 1) v += __shfl_xor(v, d);
    return v;
}
__device__ __forceinline__ float wmax(float v) {
#pragma unroll
    for (int d = 1; d < 64; d <<= 1) v = fmaxf(v, __shfl_xor(v, d));
    return v;
}
__device__ __forceinline__ float wmin(float v) {
#pragma unroll
    for (int d = 1; d < 64; d <<= 1) v = fminf(v, __shfl_xor(v, d));
    return v;
}

// Fence-free sense-reversing per-batch barrier. All WGs resident by
// construction (512 WGs, 2/CU guaranteed by LDS=64KB + VGPR<=128 cap).
// Pre-barrier stores were acked at the coherence point by each wave's own
// vmcnt(0) drain at __syncthreads; arrival atomic therefore orders after them.
__device__ __forceinline__ void batch_barrier(int* cnt, int* gen, int tid)
{
    __syncthreads();
    if (tid == 0) {
        asm volatile("s_waitcnt vmcnt(0)" ::: "memory");
        int g = aloadi(gen);
        int a = __hip_atomic_fetch_add(cnt, 1, __ATOMIC_RELAXED, __HIP_MEMORY_SCOPE_AGENT);
        if (a == WGB - 1) {
            __hip_atomic_store(cnt, 0, __ATOMIC_RELAXED, __HIP_MEMORY_SCOPE_AGENT);
            asm volatile("s_waitcnt vmcnt(0)" ::: "memory");   // reset visible before flip
            __hip_atomic_store(gen, g + 1, __ATOMIC_RELAXED, __HIP_MEMORY_SCOPE_AGENT);
        } else {
            while (aloadi(gen) == g) __builtin_amdgcn_s_sleep(1);
        }
    }
    __syncthreads();
}

// One half-iteration of log-domain Sinkhorn: this wave scans ALL columns for
// its R rows. Persistent per-row reference L[] + drift extrapolation D[]
// (L_pred = L + D) keeps the branch-free fast path valid even while the
// potentials still move; exact two-pass redo on seed (iter 0) / NaN / blowup.
__device__ __forceinline__ void half_fused(const float4* __restrict__ colbuf,
                                           const float4* __restrict__ rowbuf,
                                           float* __restrict__ outv,
                                           float* L, float* D,
                                           int nrows, int ncols, float eln,
                                           int r0, int lane)
{
    if (r0 >= nrows) return;
    const int nst = (ncols + 63) >> 6;
    const float4* cb = colbuf + lane;

    float x0[R], x1[R], x2[R], ar[R], Lp[R];
#pragma unroll
    for (int r = 0; r < R; ++r) {
        float4 s = rowbuf[r0 + r];               // broadcast read (scaled 2k*x)
        x0[r] = s.x * INV_TK; x1[r] = s.y * INV_TK; x2[r] = s.z * INV_TK;
        ar[r] = AR_SCALE * fmaf(s.x, s.x, fmaf(s.y, s.y, s.z * s.z));  // -k*xx
        Lp[r] = L[r] + D[r];                     // extrapolated reference
    }

    float S[R];
#pragma unroll
    for (int r = 0; r < R; ++r) S[r] = 0.0f;
#pragma unroll 2
    for (int s = 0; s < nst; ++s) {
        float4 yb = cb[s << 6];
#pragma unroll
        for (int r = 0; r < R; ++r) {
            float t = fmaf(x0[r], yb.x, fmaf(x1[r], yb.y, fmaf(x2[r], yb.z, yb.w)));
            S[r] += exp2fast(t - Lp[r]);
        }
    }
    float Ssum[R];
    bool redo = false;
#pragma unroll
    for (int r = 0; r < R; ++r) {
        Ssum[r] = wsum(S[r]);
        redo |= !(Ssum[r] >= 1e-30f && Ssum[r] <= 1e30f);  // 0/inf/NaN/drift>~100 log2
    }
    if (redo) {   // wave-uniform exact two-pass recompute
        float Mn[R];
#pragma unroll
        for (int r = 0; r < R; ++r) Mn[r] = -3.0e38f;
        for (int s = 0; s < nst; ++s) {
            float4 yb = cb[s << 6];
#pragma unroll
            for (int r = 0; r < R; ++r) {
                float t = fmaf(x0[r], yb.x, fmaf(x1[r], yb.y, fmaf(x2[r], yb.z, yb.w)));
                Mn[r] = fmaxf(Mn[r], t);
            }
        }
#pragma unroll
        for (int r = 0; r < R; ++r) { Lp[r] = wmax(Mn[r]); S[r] = 0.0f; }
        for (int s = 0; s < nst; ++s) {
            float4 yb = cb[s << 6];
#pragma unroll
            for (int r = 0; r < R; ++r) {
                float t = fmaf(x0[r], yb.x, fmaf(x1[r], yb.y, fmaf(x2[r], yb.z, yb.w)));
                S[r] += exp2fast(t - Lp[r]);
            }
        }
#pragma unroll
        for (int r = 0; r < R; ++r) Ssum[r] = wsum(S[r]);
    }

    float fv[R];
#pragma unroll
    for (int r = 0; r < R; ++r) {
        float lnew = Lp[r] + log2fast(Ssum[r]);          // exact LSE2
        D[r] = (L[r] > 1.0e37f) ? 0.0f : (lnew - L[r]);  // drift (0 on first iter)
        L[r] = lnew;
        fv[r] = fmaf(-EPS_LN2, ar[r] + lnew, eln);
    }
    float v = fv[0];
#pragma unroll
    for (int r = 1; r < R; ++r) v = (lane == r) ? fv[r] : v;
    if (lane < R && (r0 + lane) < nrows) astoref(&outv[r0 + lane], v);
}

__launch_bounds__(TPB, 4)   // cap VGPR at 128: guarantees 2 WG/CU residency
__global__ void pcl_kernel(const float* __restrict__ pred,
                           const float* __restrict__ gt,
                           const int* __restrict__ nlen,
                           const int* __restrict__ mlen,
                           int* __restrict__ hdr,
                           float* __restrict__ fbuf,
                           float* __restrict__ gbuf,
                           float* __restrict__ parts,
                           float* __restrict__ bres,
                           float* __restrict__ out)
{
    __shared__ float4 xbuf[NPTS];   // (2k*x, v) : 32 KB
    __shared__ float4 ybuf[NPTS];   // (2k*y, u) : 32 KB

    const int tid  = threadIdx.x;
    const int wg   = blockIdx.x;
    // batch mapping: co-resident WG pair (wg, wg+256) -> DIFFERENT batches so
    // one batch computes while the other waits at its barrier (perf heuristic
    // only; correctness independent of placement).
    const int lo   = wg & 255;
    const int hi   = wg >> 8;                 // 0 or 1
    const int b    = ((lo & 7) + hi) & 7;
    const int wloc = (lo >> 3) + hi * 32;     // 0..63 within batch
    const int wv   = tid >> 6;                // 0..7
    const int lane = tid & 63;
    const int r0   = wloc * 32 + wv * R;      // this wave's first row (0..2044)
    const int n = nlen[b];
    const int m = mlen[b];
    const float nf = (float)n, mf = (float)m;
    const float* predb = pred + (size_t)b * NPTS * 3;
    const float* gtb   = gt   + (size_t)b * NPTS * 3;
    float* fb = fbuf + b * NPTS;
    float* gb = gbuf + b * NPTS;
    int* cnt  = hdr + b * 16;        // 64 B apart: no cross-batch line sharing
    int* gen  = hdr + 128 + b * 16;
    int* done = hdr + 256;

    // stage scaled clipped clouds into LDS
    for (int idx = tid; idx < NPTS; idx += TPB) {
        const float* p = predb + (size_t)idx * 3;
        xbuf[idx] = make_float4(clipf(p[0]) * TWO_K, clipf(p[1]) * TWO_K, clipf(p[2]) * TWO_K, 0.0f);
        const float* q = gtb + (size_t)idx * 3;
        ybuf[idx] = make_float4(clipf(q[0]) * TWO_K, clipf(q[1]) * TWO_K, clipf(q[2]) * TWO_K, 0.0f);
    }

    const float eln_m = EPSV * LN2 * log2fast(mf);   // eps*ln(m)
    const float eln_n = EPSV * LN2 * log2fast(nf);   // eps*ln(n)

    float Lf[R], Lg[R], Df[R], Dg[R];
#pragma unroll
    for (int r = 0; r < R; ++r) {
        Lf[r] = 3.0e38f; Lg[r] = 3.0e38f;   // sentinel: force exact redo at iter 0
        Df[r] = 0.0f;    Dg[r] = 0.0f;
    }

    for (int it = 0; it < ITERS; ++it) {
        // u-phase: ybuf.w = k*(g - yy); iter 0 uses g == 0
        for (int j = tid; j < NPTS; j += TPB) {
            float4 yb = ybuf[j];
            float yy = fmaf(yb.x, yb.x, fmaf(yb.y, yb.y, yb.z * yb.z)) * INV_2K_SQ;
            float gval = (it == 0) ? 0.0f : aloadf(&gb[j]);
            ybuf[j].w = (j < m) ? (gval - yy) * KLOG2E : NEGU;
        }
        __syncthreads();
        half_fused(ybuf, xbuf, fb, Lf, Df, n, m, eln_m, r0, lane);   // f = update(g)
        batch_barrier(cnt, gen, tid);
        // v-phase: xbuf.w = k*(f - xx)
        for (int i = tid; i < NPTS; i += TPB) {
            float4 xb = xbuf[i];
            float xx = fmaf(xb.x, xb.x, fmaf(xb.y, xb.y, xb.z * xb.z)) * INV_2K_SQ;
            xbuf[i].w = (i < n) ? (aloadf(&fb[i]) - xx) * KLOG2E : NEGU;
        }
        __syncthreads();
        half_fused(xbuf, ybuf, gb, Lg, Dg, m, n, eln_n, r0, lane);   // g = update(f)
        batch_barrier(cnt, gen, tid);
    }

    // refresh u with final g for the cost pass
    for (int j = tid; j < NPTS; j += TPB) {
        float4 yb = ybuf[j];
        float yy = fmaf(yb.x, yb.x, fmaf(yb.y, yb.y, yb.z * yb.z)) * INV_2K_SQ;
        ybuf[j].w = (j < m) ? (aloadf(&gb[j]) - yy) * KLOG2E : NEGU;
    }
    __syncthreads();

    // ---- pass A: transport cost + chamfer x->y ----
    float wcost = 0.0f, chx = 0.0f;
    if (r0 < n) {
        float px0[R], px1[R], px2[R], pxx[R], hrow[R], dmn[R];
#pragma unroll
        for (int r = 0; r < R; ++r) {
            float4 s = xbuf[r0 + r];
            px0[r] = s.x * INV_TK; px1[r] = s.y * INV_TK; px2[r] = s.z * INV_TK;
            pxx[r] = fmaf(s.x, s.x, fmaf(s.y, s.y, s.z * s.z)) * INV_2K_SQ;
            hrow[r] = (r0 + r < n) ? (aloadf(&fb[r0 + r]) - pxx[r]) * KLOG2E : NEGU;
            dmn[r] = BIGD;
        }
        const int nst = (m + 63) >> 6;
#pragma unroll 2
        for (int s = 0; s < nst; ++s) {
            int jj = (s << 6) + lane;
            float4 yb = ybuf[jj];
            float yy = fmaf(yb.x, yb.x, fmaf(yb.y, yb.y, yb.z * yb.z)) * INV_2K_SQ;
            bool jv = jj < m;
#pragma unroll
            for (int r = 0; r < R; ++r) {
                float dots = fmaf(px0[r], yb.x, fmaf(px1[r], yb.y, px2[r] * yb.z)); // 2k*(x.y)
                float e = hrow[r] + yb.w + dots;                  // k*(f+g-C)
                float w = exp2fast(e);                            // n*m*P_ij
                float C = fmaxf(fmaf(dots, -INV_K, pxx[r] + yy), 0.0f);
                wcost = fmaf(w, C, wcost);
                dmn[r] = fminf(dmn[r], jv ? C : BIGD);
            }
        }
#pragma unroll
        for (int r = 0; r < R; ++r) {
            float d = wmin(dmn[r]);
            if (r0 + r < n) chx += d;   // lane-uniform
        }
        wcost = wsum(wcost);
    }

    // ---- pass B: chamfer y->x ----
    float chy = 0.0f;
    if (r0 < m) {
        float qy0[R], qy1[R], qy2[R], qyy[R], dmn[R];
#pragma unroll
        for (int r = 0; r < R; ++r) {
            float4 s = ybuf[r0 + r];
            qy0[r] = s.x * INV_TK; qy1[r] = s.y * INV_TK; qy2[r] = s.z * INV_TK;
            qyy[r] = fmaf(s.x, s.x, fmaf(s.y, s.y, s.z * s.z)) * INV_2K_SQ;
            dmn[r] = BIGD;
        }
        const int nst = (n + 63) >> 6;
#pragma unroll 2
        for (int s = 0; s < nst; ++s) {
            int ii = (s << 6) + lane;
            float4 xb = xbuf[ii];
            float xx = fmaf(xb.x, xb.x, fmaf(xb.y, xb.y, xb.z * xb.z)) * INV_2K_SQ;
            bool iv = ii < n;
#pragma unroll
            for (int r = 0; r < R; ++r) {
                float dots = fmaf(qy0[r], xb.x, fmaf(qy1[r], xb.y, qy2[r] * xb.z));
                float C = fmaxf(fmaf(dots, -INV_K, qyy[r] + xx), 0.0f);
                dmn[r] = fminf(dmn[r], iv ? C : BIGD);
            }
        }
#pragma unroll
        for (int r = 0; r < R; ++r) {
            float d = wmin(dmn[r]);
            if (r0 + r < m) chy += d;
        }
    }
    __syncthreads();

    // ---- WG reduce via xbuf-as-float scratch ----
    float* xs = (float*)xbuf;
    if (lane == 0) { xs[wv] = wcost; xs[8 + wv] = chx; xs[16 + wv] = chy; }
    __syncthreads();
    if (tid == 0) {
        float cs = 0.0f, cx = 0.0f, cy = 0.0f;
        for (int w = 0; w < 8; ++w) { cs += xs[w]; cx += xs[8 + w]; cy += xs[16 + w]; }
        astoref(&parts[(b * WGB + wloc) * 4 + 0], cs);
        astoref(&parts[(b * WGB + wloc) * 4 + 1], cx);
        astoref(&parts[(b * WGB + wloc) * 4 + 2], cy);
    }
    batch_barrier(cnt, gen, tid);

    // ---- batch leader reduces its 64 WGs (one per lane); last batch finishes ----
    if (wloc == 0 && wv == 0) {
        float cs = aloadf(&parts[(b * WGB + lane) * 4 + 0]);
        float cx = aloadf(&parts[(b * WGB + lane) * 4 + 1]);
        float cy = aloadf(&parts[(b * WGB + lane) * 4 + 2]);
        cs = wsum(cs); cx = wsum(cx); cy = wsum(cy);
        if (lane == 0) {
            float cost = cs / (nf * mf);
            astoref(&bres[b], sqrtf(fmaxf(cost, 0.0f)) + cx / nf + cy / mf);
            asm volatile("s_waitcnt vmcnt(0)" ::: "memory");
            int a = __hip_atomic_fetch_add(done, 1, __ATOMIC_RELAXED, __HIP_MEMORY_SCOPE_AGENT);
            if (a == BATCH - 1) {
                float acc = 0.0f;
                for (int i2 = 0; i2 < BATCH; ++i2) acc += aloadf(&bres[i2]);
                out[0] = acc * 0.125f;
            }
        }
    }
}

extern "C" void kernel_launch(void* const* d_in, const int* in_sizes, int n_in,
                              void* d_out, int out_size, void* d_ws, size_t ws_size,
                              hipStream_t stream) {
    const float* pred = (const float*)d_in[0];
    const float* gt   = (const float*)d_in[1];
    const int*  nlen  = (const int*)d_in[2];
    const int*  mlen  = (const int*)d_in[3];

    int*   hdr   = (int*)d_ws;            // cnt[b] at b*16, gen[b] at 128+b*16, done at 256
    float* base  = (float*)d_ws + 512;    // skip 2048 B of barrier state
    float* fbuf  = base;                  // 8*2048
    float* gbuf  = fbuf + BATCH * NPTS;   // 8*2048
    float* parts = gbuf + BATCH * NPTS;   // 512*4
    float* bres  = parts + NWG * 4;       // 8
    float* out   = (float*)d_out;

    hipMemsetAsync(d_ws, 0, 2048, stream);   // zero barrier state each call
    hipLaunchKernelGGL(pcl_kernel, dim3(NWG), dim3(TPB), 0, stream,
                       pred, gt, nlen, mlen, hdr, fbuf, gbuf, parts, bres, out);
}

// Round 8
// 806.180 us; speedup vs baseline: 11.0197x; 1.0368x over previous
//
#include <hip/hip_runtime.h>

#define BATCH 8
#define NPTS  2048
#define TPB   512           // 8 waves/WG, 2 WG/CU (LDS 2x64KB<=160KB), 4 waves/SIMD
#define WGB   64            // workgroups per batch
#define NWG   (BATCH*WGB)   // 512 = exact residency capacity
#define ITERS 50
#define R     4

#define KLOG2E    1442.6950408889634f    // log2(e)/eps
#define TWO_K     2885.3900817779268f    // 2*log2(e)/eps
#define INV_TK    3.4657359027997264e-4f // 1/(2k)
#define INV_K     6.931471805599453e-4f  // 1/k = eps*ln2
#define INV_2K_SQ 1.2011325347955035e-7f // 1/(2k)^2
#define AR_SCALE  -1.7328679513998632e-4f// -k/(2k)^2 = -1/(4k)
#define NEGU      -1e30f
#define BIGD      1e10f

typedef float f2 __attribute__((ext_vector_type(2)));

__device__ __forceinline__ float exp2fast(float x) { return __builtin_amdgcn_exp2f(x); }
__device__ __forceinline__ float log2fast(float x) { return __builtin_amdgcn_logf(x); }
__device__ __forceinline__ float clipf(float v)    { return fminf(fmaxf(v, -1.0f), 1.0f); }
__device__ __forceinline__ f2 bc(float x) { f2 r; r.x = x; r.y = x; return r; }

// packed fp32: ALL operands must be 64-bit VGPR pairs on gfx950
__device__ __forceinline__ f2 pk_fma(f2 a, f2 b, f2 c) {
    f2 d;
    asm("v_pk_fma_f32 %0, %1, %2, %3" : "=v"(d) : "v"(a), "v"(b), "v"(c));
    return d;
}
__device__ __forceinline__ f2 pk_add(f2 a, f2 b) {
    f2 d;
    asm("v_pk_add_f32 %0, %1, %2" : "=v"(d) : "v"(a), "v"(b));
    return d;
}

// relaxed agent-scope atomics: coherent at LLC, no fences/cache-nukes needed
__device__ __forceinline__ float aloadf(const float* p) {
    return __hip_atomic_load(p, __ATOMIC_RELAXED, __HIP_MEMORY_SCOPE_AGENT);
}
__device__ __forceinline__ void astoref(float* p, float v) {
    __hip_atomic_store(p, v, __ATOMIC_RELAXED, __HIP_MEMORY_SCOPE_AGENT);
}
__device__ __forceinline__ int aloadi(const int* p) {
    return __hip_atomic_load(p, __ATOMIC_RELAXED, __HIP_MEMORY_SCOPE_AGENT);
}
__device__ __forceinline__ void astorei(int* p, int v) {
    __hip_atomic_store(p, v, __ATOMIC_RELAXED, __HIP_MEMORY_SCOPE_AGENT);
}

__device__ __forceinline__ float wsum(float v) {
#pragma unroll
    for (int d = 1; d < 64; d <<= 1) v += __shfl_xor(v, d);
    return v;
}
__device__ __forceinline__ float wmax(float v) {
#pragma unroll
    for (int d = 1; d < 64; d <<= 1) v = fmaxf(v, __shfl_xor(v, d));
    return v;
}
__device__ __forceinline__ float wmin(float v) {
#pragma unroll
    for (int d = 1; d < 64; d <<= 1) v = fminf(v, __shfl_xor(v, d));
    return v;
}

// Two-level fence-free sense-reversing barrier: 8 sub-counters (8 WGs each) +
// one top counter, each in its own 64B line. All WGs resident by construction.
__device__ __forceinline__ void batch_barrier(int* subs_base, int* sub, int* top,
                                              int* gen, int tid)
{
    __syncthreads();
    if (tid == 0) {
        asm volatile("s_waitcnt vmcnt(0)" ::: "memory");   // WG's stores at LLC
        int g = aloadi(gen);
        int a = __hip_atomic_fetch_add(sub, 1, __ATOMIC_RELAXED, __HIP_MEMORY_SCOPE_AGENT);
        if (a == 7) {
            int t = __hip_atomic_fetch_add(top, 1, __ATOMIC_RELAXED, __HIP_MEMORY_SCOPE_AGENT);
            if (t == 7) {
#pragma unroll
                for (int s = 0; s < 8; ++s) astorei(subs_base + s * 16, 0);
                astorei(top, 0);
                asm volatile("s_waitcnt vmcnt(0)" ::: "memory");   // resets visible first
                astorei(gen, g + 1);
            } else {
                while (aloadi(gen) == g) __builtin_amdgcn_s_sleep(1);
            }
        } else {
            while (aloadi(gen) == g) __builtin_amdgcn_s_sleep(1);
        }
    }
    __syncthreads();
}

// One Sinkhorn half-iteration, packed-pair inner loop. Columns in planar f2
// LDS (cx,cy,cz scaled 2k; cw = u of other side, NEGU-padded). Rows re-derived
// from own-side planes. Persistent log2 ref L[] + drift D[]; exact 2-pass redo
// on seed/NaN/blowup. Output: u_row = L2C - lnew (u-domain, xx folded away).
__device__ __forceinline__ void half_fused_pk(
    const f2* __restrict__ cx, const f2* __restrict__ cy,
    const f2* __restrict__ cz, const f2* __restrict__ cw,
    const f2* __restrict__ rx, const f2* __restrict__ ry, const f2* __restrict__ rz,
    float* __restrict__ uout, float L2C, float* L, float* D,
    int nrows, int ncols, int r0, int lane)
{
    if (r0 >= nrows) return;
    const int nst = (ncols + 127) >> 7;   // pairs: 64 lanes -> 128 cols/step
    const int rp = r0 >> 1;
    f2 vx0 = rx[rp], vx1 = rx[rp + 1];
    f2 vy0 = ry[rp], vy1 = ry[rp + 1];
    f2 vz0 = rz[rp], vz1 = rz[rp + 1];
    // broadcast pairs (row scalars replicated into both halves)
    f2 x0p[R] = { bc(vx0.x * INV_TK), bc(vx0.y * INV_TK), bc(vx1.x * INV_TK), bc(vx1.y * INV_TK) };
    f2 x1p[R] = { bc(vy0.x * INV_TK), bc(vy0.y * INV_TK), bc(vy1.x * INV_TK), bc(vy1.y * INV_TK) };
    f2 x2p[R] = { bc(vz0.x * INV_TK), bc(vz0.y * INV_TK), bc(vz1.x * INV_TK), bc(vz1.y * INV_TK) };

    float Lp[R];
    f2 nLp[R];
#pragma unroll
    for (int r = 0; r < R; ++r) { Lp[r] = L[r] + D[r]; nLp[r] = bc(-Lp[r]); }

    float S0[R], S1[R];
#pragma unroll
    for (int r = 0; r < R; ++r) { S0[r] = 0.0f; S1[r] = 0.0f; }

    for (int s = 0; s < nst; ++s) {
        int p = (s << 6) + lane;
        f2 bx = cx[p], by = cy[p], bz = cz[p], bw = cw[p];
#pragma unroll
        for (int r = 0; r < R; ++r) {
            f2 t = pk_fma(x2p[r], bz, bw);
            t = pk_fma(x1p[r], by, t);
            t = pk_fma(x0p[r], bx, t);
            t = pk_add(nLp[r], t);
            S0[r] += exp2fast(t.x);
            S1[r] += exp2fast(t.y);
        }
    }

    float Ssum[R];
    bool redo = false;
#pragma unroll
    for (int r = 0; r < R; ++r) {
        Ssum[r] = wsum(S0[r] + S1[r]);
        redo |= !(Ssum[r] >= 1e-30f && Ssum[r] <= 1e30f);   // 0/inf/NaN/drift
    }
    if (redo) {   // wave-uniform exact two-pass recompute
        float Mn[R];
#pragma unroll
        for (int r = 0; r < R; ++r) Mn[r] = -3.0e38f;
        for (int s = 0; s < nst; ++s) {
            int p = (s << 6) + lane;
            f2 bx = cx[p], by = cy[p], bz = cz[p], bw = cw[p];
#pragma unroll
            for (int r = 0; r < R; ++r) {
                f2 t = pk_fma(x2p[r], bz, bw);
                t = pk_fma(x1p[r], by, t);
                t = pk_fma(x0p[r], bx, t);
                Mn[r] = fmaxf(Mn[r], fmaxf(t.x, t.y));
            }
        }
#pragma unroll
        for (int r = 0; r < R; ++r) {
            Lp[r] = wmax(Mn[r]); nLp[r] = bc(-Lp[r]);
            S0[r] = 0.0f; S1[r] = 0.0f;
        }
        for (int s = 0; s < nst; ++s) {
            int p = (s << 6) + lane;
            f2 bx = cx[p], by = cy[p], bz = cz[p], bw = cw[p];
#pragma unroll
            for (int r = 0; r < R; ++r) {
                f2 t = pk_fma(x2p[r], bz, bw);
                t = pk_fma(x1p[r], by, t);
                t = pk_fma(x0p[r], bx, t);
                t = pk_add(nLp[r], t);
                S0[r] += exp2fast(t.x);
                S1[r] += exp2fast(t.y);
            }
        }
#pragma unroll
        for (int r = 0; r < R; ++r) Ssum[r] = wsum(S0[r] + S1[r]);
    }

    float uv[R];
#pragma unroll
    for (int r = 0; r < R; ++r) {
        float lnew = Lp[r] + log2fast(Ssum[r]);          // exact LSE2
        D[r] = (L[r] > 1.0e37f) ? 0.0f : (lnew - L[r]);  // drift (0 on seed)
        L[r] = lnew;
        uv[r] = L2C - lnew;                              // u-domain output
    }
    float v = uv[0];
#pragma unroll
    for (int r = 1; r < R; ++r) v = (lane == r) ? uv[r] : v;
    if (lane < R && (r0 + lane) < nrows) astoref(&uout[r0 + lane], v);
}

__launch_bounds__(TPB, 4)   // 4 waves/SIMD -> 128 VGPR cap, guarantees 2 WG/CU
__global__ void pcl_kernel(const float* __restrict__ pred,
                           const float* __restrict__ gt,
                           const int* __restrict__ nlen,
                           const int* __restrict__ mlen,
                           int* __restrict__ hdr,
                           float* __restrict__ fbuf,
                           float* __restrict__ gbuf,
                           float* __restrict__ parts,
                           float* __restrict__ bres,
                           float* __restrict__ out)
{
    // planar component LDS: pairs of columns per entry (8 x 8KB = 64KB)
    __shared__ f2 XSX[NPTS/2], XSY[NPTS/2], XSZ[NPTS/2], XSW[NPTS/2];
    __shared__ f2 YSX[NPTS/2], YSY[NPTS/2], YSZ[NPTS/2], YSW[NPTS/2];

    const int tid  = threadIdx.x;
    const int wg   = blockIdx.x;
    // co-resident WG pair (wg, wg+256) -> different batches (overlap heuristic)
    const int lo   = wg & 255;
    const int hi   = wg >> 8;
    const int b    = ((lo & 7) + hi) & 7;
    const int wloc = (lo >> 3) + hi * 32;     // 0..63 within batch
    const int wv   = tid >> 6;                // 0..7
    const int lane = tid & 63;
    const int r0   = wloc * 32 + wv * R;      // first row (0..2044)
    const int n = nlen[b];
    const int m = mlen[b];
    const float nf = (float)n, mf = (float)m;
    const float* predb = pred + (size_t)b * NPTS * 3;
    const float* gtb   = gt   + (size_t)b * NPTS * 3;
    float* fb = fbuf + b * NPTS;
    float* gb = gbuf + b * NPTS;
    int* subs_base = hdr + b * 128;                    // 8 lines
    int* sub       = subs_base + (wloc >> 3) * 16;
    int* top       = hdr + (64 + b) * 16;
    int* gen       = hdr + (72 + b) * 16;
    int* done      = hdr + 80 * 16;

    // stage scaled clipped clouds into planar LDS
    for (int idx = tid; idx < NPTS; idx += TPB) {
        const float* p = predb + (size_t)idx * 3;
        ((float*)XSX)[idx] = clipf(p[0]) * TWO_K;
        ((float*)XSY)[idx] = clipf(p[1]) * TWO_K;
        ((float*)XSZ)[idx] = clipf(p[2]) * TWO_K;
        const float* q = gtb + (size_t)idx * 3;
        ((float*)YSX)[idx] = clipf(q[0]) * TWO_K;
        ((float*)YSY)[idx] = clipf(q[1]) * TWO_K;
        ((float*)YSZ)[idx] = clipf(q[2]) * TWO_K;
    }
    __syncthreads();

    const float L2M = log2fast(mf);
    const float L2N = log2fast(nf);

    float Lf[R], Lg[R], Df[R], Dg[R];
#pragma unroll
    for (int r = 0; r < R; ++r) {
        Lf[r] = 3.0e38f; Lg[r] = 3.0e38f;   // sentinel: exact redo at iter 0
        Df[r] = 0.0f;    Dg[r] = 0.0f;
    }

    for (int it = 0; it < ITERS; ++it) {
        // u-phase: YSW[j] = u_g(j) (pure copy; iter 0: u = -k*yy from planes)
        if (it == 0) {
            for (int j = tid; j < NPTS; j += TPB) {
                float sx = ((float*)YSX)[j], sy = ((float*)YSY)[j], sz = ((float*)YSZ)[j];
                float u0 = AR_SCALE * fmaf(sx, sx, fmaf(sy, sy, sz * sz));
                ((float*)YSW)[j] = (j < m) ? u0 : NEGU;
            }
        } else {
            for (int j = tid; j < NPTS; j += TPB)
                ((float*)YSW)[j] = (j < m) ? aloadf(&gb[j]) : NEGU;
        }
        __syncthreads();
        half_fused_pk(YSX, YSY, YSZ, YSW, XSX, XSY, XSZ, fb, L2M, Lf, Df, n, m, r0, lane);
        batch_barrier(subs_base, sub, top, gen, tid);
        // v-phase: XSW[i] = u_f(i) (pure copy)
        for (int i = tid; i < NPTS; i += TPB)
            ((float*)XSW)[i] = (i < n) ? aloadf(&fb[i]) : NEGU;
        __syncthreads();
        half_fused_pk(XSX, XSY, XSZ, XSW, YSX, YSY, YSZ, gb, L2N, Lg, Dg, m, n, r0, lane);
        batch_barrier(subs_base, sub, top, gen, tid);
    }

    // refresh YSW with final g for the cost pass
    for (int j = tid; j < NPTS; j += TPB)
        ((float*)YSW)[j] = (j < m) ? aloadf(&gb[j]) : NEGU;
    __syncthreads();

    // ---- pass A: transport cost + chamfer x->y ----
    float wcost = 0.0f, chx = 0.0f;
    if (r0 < n) {
        const int rp = r0 >> 1;
        f2 vx0 = XSX[rp], vx1 = XSX[rp + 1];
        f2 vy0 = XSY[rp], vy1 = XSY[rp + 1];
        f2 vz0 = XSZ[rp], vz1 = XSZ[rp + 1];
        float px0[R] = { vx0.x * INV_TK, vx0.y * INV_TK, vx1.x * INV_TK, vx1.y * INV_TK };
        float px1[R] = { vy0.x * INV_TK, vy0.y * INV_TK, vy1.x * INV_TK, vy1.y * INV_TK };
        float px2[R] = { vz0.x * INV_TK, vz0.y * INV_TK, vz1.x * INV_TK, vz1.y * INV_TK };
        float pxx[R], hrow[R];
        f2 dmn[R];
#pragma unroll
        for (int r = 0; r < R; ++r) {
            float sx = px0[r] * TWO_K, sy = px1[r] * TWO_K, sz = px2[r] * TWO_K;
            pxx[r] = fmaf(sx, sx, fmaf(sy, sy, sz * sz)) * INV_2K_SQ;
            hrow[r] = (r0 + r < n) ? aloadf(&fb[r0 + r]) : NEGU;   // u_f directly
            dmn[r].x = BIGD; dmn[r].y = BIGD;
        }
        const int nst = (m + 127) >> 7;
        for (int s = 0; s < nst; ++s) {
            int p = (s << 6) + lane;
            f2 bx = YSX[p], by = YSY[p], bz = YSZ[p], bw = YSW[p];
            f2 yy2 = (bx * bx + by * by + bz * bz) * INV_2K_SQ;
            bool jv0 = (2 * p)     < m;
            bool jv1 = (2 * p + 1) < m;
#pragma unroll
            for (int r = 0; r < R; ++r) {
                f2 dots = px0[r] * bx + px1[r] * by + px2[r] * bz;   // 2k*(x.y)
                f2 e = dots + bw + hrow[r];                          // k*(f+g-C)
                float w0 = exp2fast(e.x), w1 = exp2fast(e.y);        // n*m*P
                f2 C;
                C.x = fmaxf(fmaf(dots.x, -INV_K, pxx[r] + yy2.x), 0.0f);
                C.y = fmaxf(fmaf(dots.y, -INV_K, pxx[r] + yy2.y), 0.0f);
                wcost = fmaf(w0, C.x, fmaf(w1, C.y, wcost));
                dmn[r].x = fminf(dmn[r].x, jv0 ? C.x : BIGD);
                dmn[r].y = fminf(dmn[r].y, jv1 ? C.y : BIGD);
            }
        }
#pragma unroll
        for (int r = 0; r < R; ++r) {
            float d = wmin(fminf(dmn[r].x, dmn[r].y));
            if (r0 + r < n) chx += d;   // lane-uniform
        }
        wcost = wsum(wcost);
    }

    // ---- pass B: chamfer y->x ----
    float chy = 0.0f;
    if (r0 < m) {
        const int rp = r0 >> 1;
        f2 vx0 = YSX[rp], vx1 = YSX[rp + 1];
        f2 vy0 = YSY[rp], vy1 = YSY[rp + 1];
        f2 vz0 = YSZ[rp], vz1 = YSZ[rp + 1];
        float qy0[R] = { vx0.x * INV_TK, vx0.y * INV_TK, vx1.x * INV_TK, vx1.y * INV_TK };
        float qy1[R] = { vy0.x * INV_TK, vy0.y * INV_TK, vy1.x * INV_TK, vy1.y * INV_TK };
        float qy2[R] = { vz0.x * INV_TK, vz0.y * INV_TK, vz1.x * INV_TK, vz1.y * INV_TK };
        float qyy[R];
        f2 dmn[R];
#pragma unroll
        for (int r = 0; r < R; ++r) {
            float sx = qy0[r] * TWO_K, sy = qy1[r] * TWO_K, sz = qy2[r] * TWO_K;
            qyy[r] = fmaf(sx, sx, fmaf(sy, sy, sz * sz)) * INV_2K_SQ;
            dmn[r].x = BIGD; dmn[r].y = BIGD;
        }
        const int nst = (n + 127) >> 7;
        for (int s = 0; s < nst; ++s) {
            int p = (s << 6) + lane;
            f2 bx = XSX[p], by = XSY[p], bz = XSZ[p];
            f2 xx2 = (bx * bx + by * by + bz * bz) * INV_2K_SQ;
            bool iv0 = (2 * p)     < n;
            bool iv1 = (2 * p + 1) < n;
#pragma unroll
            for (int r = 0; r < R; ++r) {
                f2 dots = qy0[r] * bx + qy1[r] * by + qy2[r] * bz;
                f2 C;
                C.x = fmaxf(fmaf(dots.x, -INV_K, qyy[r] + xx2.x), 0.0f);
                C.y = fmaxf(fmaf(dots.y, -INV_K, qyy[r] + xx2.y), 0.0f);
                dmn[r].x = fminf(dmn[r].x, iv0 ? C.x : BIGD);
                dmn[r].y = fminf(dmn[r].y, iv1 ? C.y : BIGD);
            }
        }
#pragma unroll
        for (int r = 0; r < R; ++r) {
            float d = wmin(fminf(dmn[r].x, dmn[r].y));
            if (r0 + r < m) chy += d;
        }
    }
    __syncthreads();

    // ---- WG reduce via XSX-as-float scratch ----
    float* xs = (float*)XSX;
    if (lane == 0) { xs[wv] = wcost; xs[8 + wv] = chx; xs[16 + wv] = chy; }
    __syncthreads();
    if (tid == 0) {
        float cs = 0.0f, cx = 0.0f, cy = 0.0f;
        for (int w = 0; w < 8; ++w) { cs += xs[w]; cx += xs[8 + w]; cy += xs[16 + w]; }
        astoref(&parts[(b * WGB + wloc) * 4 + 0], cs);
        astoref(&parts[(b * WGB + wloc) * 4 + 1], cx);
        astoref(&parts[(b * WGB + wloc) * 4 + 2], cy);
    }
    batch_barrier(subs_base, sub, top, gen, tid);

    // ---- batch leader reduces its 64 WGs; last batch finishes ----
    if (wloc == 0 && wv == 0) {
        float cs = aloadf(&parts[(b * WGB + lane) * 4 + 0]);
        float cx = aloadf(&parts[(b * WGB + lane) * 4 + 1]);
        float cy = aloadf(&parts[(b * WGB + lane) * 4 + 2]);
        cs = wsum(cs); cx = wsum(cx); cy = wsum(cy);
        if (lane == 0) {
            float cost = cs / (nf * mf);
            astoref(&bres[b], sqrtf(fmaxf(cost, 0.0f)) + cx / nf + cy / mf);
            asm volatile("s_waitcnt vmcnt(0)" ::: "memory");
            int a = __hip_atomic_fetch_add(done, 1, __ATOMIC_RELAXED, __HIP_MEMORY_SCOPE_AGENT);
            if (a == BATCH - 1) {
                float acc = 0.0f;
                for (int i2 = 0; i2 < BATCH; ++i2) acc += aloadf(&bres[i2]);
                out[0] = acc * 0.125f;
            }
        }
    }
}

extern "C" void kernel_launch(void* const* d_in, const int* in_sizes, int n_in,
                              void* d_out, int out_size, void* d_ws, size_t ws_size,
                              hipStream_t stream) {
    const float* pred = (const float*)d_in[0];
    const float* gt   = (const float*)d_in[1];
    const int*  nlen  = (const int*)d_in[2];
    const int*  mlen  = (const int*)d_in[3];

    int*   hdr   = (int*)d_ws;            // 81 x 64B lines of barrier state
    float* base  = (float*)d_ws + 2048;   // skip 8 KB
    float* fbuf  = base;                  // 8*2048 (u-domain f)
    float* gbuf  = fbuf + BATCH * NPTS;   // 8*2048 (u-domain g)
    float* parts = gbuf + BATCH * NPTS;   // 512*4
    float* bres  = parts + NWG * 4;       // 8
    float* out   = (float*)d_out;

    hipMemsetAsync(d_ws, 0, 8192, stream);   // zero barrier state each call
    hipLaunchKernelGGL(pcl_kernel, dim3(NWG), dim3(TPB), 0, stream,
                       pred, gt, nlen, mlen, hdr, fbuf, gbuf, parts, bres, out);
}